// Round 3
// baseline (1009.998 us; speedup 1.0000x reference)
//
#include <hip/hip_runtime.h>
#include <cstdint>

// CapsuleLayer dynamic routing, MI355X. B=16,N=64,I=2048,D=32,E=16,R=3.
// b-logits = (sum_j v_j).u_hat -> never materialize b or u_hat; 3 streaming
// passes over W (256MB each). Wave = one (n,i) tile: coalesced 1KB W loads,
// DPP quad_perm reduce-scatter over e-quarters. Register-pressure-shaped:
// b processed in quads (p arrays = 4), u_hat recomputed after softmax from
// L1/L2-resident W instead of being held across the barrier. launch_bounds
// (1024,4) -> 128 VGPR cap, no scratch spills.

#define B_ 16
#define N_ 64
#define I_ 2048
#define D_ 32
#define E_ 16
#define EPS_ 1e-7f
#define IPER_ 8
#define GRID_ 256
#define SROW_ 2048          // b-stride in s = N_*D_
#define NOUT_ 32768         // B_*N_*D_
#define PSTRIDE_ 32768      // floats per block partial
#define WN4_ 262144         // float4 stride between n planes = I_*128

template <int CTRL>
__device__ __forceinline__ float dppf(float v) {
  return __int_as_float(
      __builtin_amdgcn_update_dpp(0, __float_as_int(v), CTRL, 0xF, 0xF, true));
}
// DPP ctrl: quad_perm[1,0,3,2]=0xB1 (xor1), quad_perm[2,3,0,1]=0x4E (xor2),
// row_ror:4=0x124, row_ror:8=0x128 (rows = 16 lanes).

// u_hat for b-chunk k: lane ends owning b=4k+q, d=dd (u0) and d=dd+16 (u1).
__device__ __forceinline__ void chunk_u(const float4 wa0, const float4 wa1,
                                        const float4* __restrict__ xg,
                                        int k, int q, float& u0, float& u1)
{
  float p0[4], p1[4];
#pragma unroll
  for (int j = 0; j < 4; ++j) {
    const float4 xv = xg[(size_t)(4 * k + j) * 8192];
    p0[j] = wa0.x * xv.x + wa0.y * xv.y + wa0.z * xv.z + wa0.w * xv.w;
    p1[j] = wa1.x * xv.x + wa1.y * xv.y + wa1.z * xv.z + wa1.w * xv.w;
  }
  {
    const float r0 = p0[0] + dppf<0xB1>(p0[0]);
    const float r1 = p0[1] + dppf<0xB1>(p0[1]);
    const float r2 = p0[2] + dppf<0xB1>(p0[2]);
    const float r3 = p0[3] + dppf<0xB1>(p0[3]);
    const float sa = (q & 1) ? r1 : r0;
    const float sb = (q & 1) ? r3 : r2;
    const float a0 = sa + dppf<0x4E>(sa);
    const float a1 = sb + dppf<0x4E>(sb);
    u0 = (q & 2) ? a1 : a0;
  }
  {
    const float r0 = p1[0] + dppf<0xB1>(p1[0]);
    const float r1 = p1[1] + dppf<0xB1>(p1[1]);
    const float r2 = p1[2] + dppf<0xB1>(p1[2]);
    const float r3 = p1[3] + dppf<0xB1>(p1[3]);
    const float sa = (q & 1) ? r1 : r0;
    const float sb = (q & 1) ? r3 : r2;
    const float a0 = sa + dppf<0x4E>(sa);
    const float a1 = sb + dppf<0x4E>(sb);
    u1 = (q & 2) ? a1 : a0;
  }
}

// MODE 0: c = 1/64 (softmax of zero logits), no barriers in i-loop.
// MODE 1: logits = vtot . u_hat, softmax over n within block, recompute u.
template <int MODE>
__global__ __launch_bounds__(1024, 4) void caps_pass(
    const float* __restrict__ W,     // [N][I][D][E]
    const float* __restrict__ x,     // [B][I][E]
    const float* __restrict__ vtot,  // [B][N][D]
    float* __restrict__ out,         // partials base or s (atomic)
    int use_part)
{
  const int t = threadIdx.x;
  const int w = t >> 6;      // wave 0..15 -> n = 4w+nn
  const int l = t & 63;
  const int q = l & 3;       // e-quarter
  const int dd = l >> 2;     // d (0..15); also owns d+16

  __shared__ float l2[N_ * 65];      // logit row-partials [n][b][row4], pad
  __shared__ float c_lds[N_ * 17];   // c [n][b], pad

  float acc0[4][4], acc1[4][4];      // [nn][k], b=4k+q, d=dd / dd+16
#pragma unroll
  for (int nn = 0; nn < 4; ++nn)
#pragma unroll
    for (int k = 0; k < 4; ++k) { acc0[nn][k] = 0.f; acc1[nn][k] = 0.f; }

  const int i0 = blockIdx.x * IPER_;
  for (int ii = 0; ii < IPER_; ++ii) {
    const int i = i0 + ii;
    // x[b,i,4q..4q+3] as float4: index b*8192 + i*4 + q
    const float4* xg = (const float4*)x + (size_t)i * 4 + q;
    const float4* Wbase = (const float4*)W + (((size_t)(4 * w) * I_ + i) << 7);

    // ---- phase A: logits (MODE1) / accumulate (MODE0) ----
    {
      float4 wa0 = Wbase[l], wa1 = Wbase[64 + l];
#pragma unroll
      for (int nn = 0; nn < 4; ++nn) {
        float4 wb0, wb1;
        if (nn < 3) {
          const float4* Wn = Wbase + (size_t)(nn + 1) * WN4_;
          wb0 = Wn[l]; wb1 = Wn[64 + l];
        }
        const int n = 4 * w + nn;
#pragma unroll
        for (int k = 0; k < 4; ++k) {
          float u0, u1;
          chunk_u(wa0, wa1, xg, k, q, u0, u1);
          if (MODE == 0) {
            acc0[nn][k] += u0;
            acc1[nn][k] += u1;
          } else {
            const int b = 4 * k + q;
            const size_t va = (size_t)b * SROW_ + (size_t)n * D_ + dd;
            float lp = vtot[va] * u0 + vtot[va + 16] * u1;
            lp += dppf<0x124>(lp);   // + ror4
            lp += dppf<0x128>(lp);   // + ror8 -> sum over row's 4 dd
            if ((l & 12) == 0)       // one writer per (row, q)
              l2[n * 65 + b * 4 + (l >> 4)] = lp;
          }
        }
        if (nn < 3) { wa0 = wb0; wa1 = wb1; }
      }
    }

    if (MODE == 1) {
      __syncthreads();
      {
        // wave bw handles b=bw, lane j = n
        const int bw = t >> 6, j = t & 63;
        const int base = j * 65 + bw * 4;
        const float raw = l2[base] + l2[base + 1] + l2[base + 2] + l2[base + 3];
        float m = raw;
#pragma unroll
        for (int off = 32; off; off >>= 1) m = fmaxf(m, __shfl_xor(m, off));
        const float e = __expf(raw - m);
        float den = e;
#pragma unroll
        for (int off = 32; off; off >>= 1) den += __shfl_xor(den, off);
        c_lds[j * 17 + bw] = e / den;
      }
      __syncthreads();

      // ---- phase B: recompute u_hat (W reload hits L1/L2), accumulate ----
      float4 wa0 = Wbase[l], wa1 = Wbase[64 + l];
#pragma unroll
      for (int nn = 0; nn < 4; ++nn) {
        float4 wb0, wb1;
        if (nn < 3) {
          const float4* Wn = Wbase + (size_t)(nn + 1) * WN4_;
          wb0 = Wn[l]; wb1 = Wn[64 + l];
        }
        const int n = 4 * w + nn;
#pragma unroll
        for (int k = 0; k < 4; ++k) {
          float u0, u1;
          chunk_u(wa0, wa1, xg, k, q, u0, u1);
          const float cc = c_lds[n * 17 + 4 * k + q];
          acc0[nn][k] += cc * u0;
          acc1[nn][k] += cc * u1;
        }
        if (nn < 3) { wa0 = wb0; wa1 = wb1; }
      }
    }
  }

  // store: partial slice (non-atomic) or atomic accumulate
  const float sc = (MODE == 0) ? (1.f / 64.f) : 1.f;
  float* base = out + (use_part ? (size_t)blockIdx.x * PSTRIDE_ : 0);
#pragma unroll
  for (int nn = 0; nn < 4; ++nn) {
#pragma unroll
    for (int k = 0; k < 4; ++k) {
      const int b = 4 * k + q, n = 4 * w + nn;
      const size_t a = (size_t)b * SROW_ + (size_t)n * D_ + dd;
      if (use_part) {
        base[a] = acc0[nn][k] * sc;
        base[a + 16] = acc1[nn][k] * sc;
      } else {
        atomicAdd(&base[a], acc0[nn][k] * sc);
        atomicAdd(&base[a + 16], acc1[nn][k] * sc);
      }
    }
  }
}

__global__ void reduce_partials(const float* __restrict__ part,
                                float* __restrict__ s)
{
  const int t = blockIdx.x * blockDim.x + threadIdx.x;  // 32768 threads
  float sum = 0.f;
#pragma unroll 4
  for (int b = 0; b < GRID_; ++b) sum += part[(size_t)b * PSTRIDE_ + t];
  s[t] = sum;
}

// vtot[row] += squash(s[row]); rows are (b*64+n), 32 floats each
__global__ void caps_squash_acc(const float* __restrict__ s_in,
                                float* __restrict__ vtot)
{
  const int t = blockIdx.x * blockDim.x + threadIdx.x;
  if (t >= B_ * N_) return;
  float v[D_];
  float s2 = 0.f;
#pragma unroll
  for (int d = 0; d < D_; ++d) {
    v[d] = s_in[(size_t)t * D_ + d];
    s2 += v[d] * v[d];
  }
  const float f = s2 / ((1.f + s2) * sqrtf(s2 + EPS_));
#pragma unroll
  for (int d = 0; d < D_; ++d) vtot[(size_t)t * D_ + d] += v[d] * f;
}

__global__ void caps_squash_final(float* __restrict__ s_io)
{
  const int t = blockIdx.x * blockDim.x + threadIdx.x;
  if (t >= B_ * N_) return;
  float v[D_];
  float s2 = 0.f;
#pragma unroll
  for (int d = 0; d < D_; ++d) {
    v[d] = s_io[(size_t)t * D_ + d];
    s2 += v[d] * v[d];
  }
  const float f = s2 / ((1.f + s2) * sqrtf(s2 + EPS_));
#pragma unroll
  for (int d = 0; d < D_; ++d) s_io[(size_t)t * D_ + d] = v[d] * f;
}

extern "C" void kernel_launch(void* const* d_in, const int* in_sizes, int n_in,
                              void* d_out, int out_size, void* d_ws, size_t ws_size,
                              hipStream_t stream)
{
  const float* x = (const float*)d_in[0];  // [16][2048][16]
  const float* W = (const float*)d_in[1];  // [64][2048][32][16]
  float* s = (float*)d_out;                // [b][n][d] accumulator / output
  float* vtot = (float*)d_ws;              // 32768 floats
  float* part = vtot + NOUT_;              // 256 * 32768 floats if available

  const size_t need = ((size_t)NOUT_ + (size_t)GRID_ * PSTRIDE_) * sizeof(float);
  const int use_part = (ws_size >= need) ? 1 : 0;
  float* pass_out = use_part ? part : s;

  const size_t sbytes = (size_t)NOUT_ * sizeof(float);
  hipMemsetAsync(vtot, 0, sbytes, stream);

  // Round 1: c = 1/64
  if (!use_part) hipMemsetAsync(s, 0, sbytes, stream);
  caps_pass<0><<<GRID_, 1024, 0, stream>>>(W, x, vtot, pass_out, use_part);
  if (use_part) reduce_partials<<<128, 256, 0, stream>>>(part, s);
  caps_squash_acc<<<4, 256, 0, stream>>>(s, vtot);          // vtot = v0

  // Round 2: logits = v0 . u_hat
  if (!use_part) hipMemsetAsync(s, 0, sbytes, stream);
  caps_pass<1><<<GRID_, 1024, 0, stream>>>(W, x, vtot, pass_out, use_part);
  if (use_part) reduce_partials<<<128, 256, 0, stream>>>(part, s);
  caps_squash_acc<<<4, 256, 0, stream>>>(s, vtot);          // vtot = v0+v1

  // Round 3: logits = (v0+v1) . u_hat -> final squash in place
  if (!use_part) hipMemsetAsync(s, 0, sbytes, stream);
  caps_pass<1><<<GRID_, 1024, 0, stream>>>(W, x, vtot, pass_out, use_part);
  if (use_part) reduce_partials<<<128, 256, 0, stream>>>(part, s);
  caps_squash_final<<<4, 256, 0, stream>>>(s);
}

// Round 4
// 419.086 us; speedup vs baseline: 2.4100x; 2.4100x over previous
//
#include <hip/hip_runtime.h>
#include <cstdint>

// CapsuleLayer dynamic routing, MI355X. B=16,N=64,I=2048,D=32,E=16,R=3.
// b-logits = (sum_j v_j).u_hat -> never materialize b or u_hat in HBM;
// 3 streaming passes over W (256MB each), ONE W read per pass:
// per i, phase A computes u_hat (coalesced 1KB W loads, DPP quad_perm
// reduce-scatter) and stashes the full 128KB u_hat tile in LDS; after the
// in-block softmax, phase B re-reads the stash (LDS-only) and accumulates.
// x staged in LDS so the inner loop's vmcnt tracks only W loads.
// 149.5KB LDS -> 1 block/CU; amdgpu_waves_per_eu(4,4) pins VGPR budget 128.

#define B_ 16
#define N_ 64
#define I_ 2048
#define D_ 32
#define E_ 16
#define EPS_ 1e-7f
#define IPER_ 8
#define GRID_ 256
#define SROW_ 2048          // b-stride in s = N_*D_
#define NOUT_ 32768         // B_*N_*D_
#define PSTRIDE_ 32768      // floats per block partial
#define WN4_ 262144         // float4 stride between n planes = I_*128

template <int CTRL>
__device__ __forceinline__ float dppf(float v) {
  return __int_as_float(
      __builtin_amdgcn_update_dpp(0, __float_as_int(v), CTRL, 0xF, 0xF, true));
}
// DPP ctrl: quad_perm[1,0,3,2]=0xB1 (xor1), quad_perm[2,3,0,1]=0x4E (xor2),
// row_ror:4=0x124, row_ror:8=0x128 (rows = 16 lanes).

// u_hat for b-chunk k: lane ends owning b=4k+q, d=dd (u0) and d=dd+16 (u1).
__device__ __forceinline__ void chunk_u(const float4 wa0, const float4 wa1,
                                        const float* __restrict__ x_lds,
                                        int k, int q, float& u0, float& u1)
{
  float p0[4], p1[4];
#pragma unroll
  for (int j = 0; j < 4; ++j) {
    const float4 xv = *(const float4*)&x_lds[(4 * k + j) * E_ + 4 * q];
    p0[j] = wa0.x * xv.x + wa0.y * xv.y + wa0.z * xv.z + wa0.w * xv.w;
    p1[j] = wa1.x * xv.x + wa1.y * xv.y + wa1.z * xv.z + wa1.w * xv.w;
  }
  {
    const float r0 = p0[0] + dppf<0xB1>(p0[0]);
    const float r1 = p0[1] + dppf<0xB1>(p0[1]);
    const float r2 = p0[2] + dppf<0xB1>(p0[2]);
    const float r3 = p0[3] + dppf<0xB1>(p0[3]);
    const float sa = (q & 1) ? r1 : r0;
    const float sb = (q & 1) ? r3 : r2;
    const float a0 = sa + dppf<0x4E>(sa);
    const float a1 = sb + dppf<0x4E>(sb);
    u0 = (q & 2) ? a1 : a0;
  }
  {
    const float r0 = p1[0] + dppf<0xB1>(p1[0]);
    const float r1 = p1[1] + dppf<0xB1>(p1[1]);
    const float r2 = p1[2] + dppf<0xB1>(p1[2]);
    const float r3 = p1[3] + dppf<0xB1>(p1[3]);
    const float sa = (q & 1) ? r1 : r0;
    const float sb = (q & 1) ? r3 : r2;
    const float a0 = sa + dppf<0x4E>(sa);
    const float a1 = sb + dppf<0x4E>(sb);
    u1 = (q & 2) ? a1 : a0;
  }
}

// MODE 0: c = 1/64 (softmax of zero logits), accumulate directly.
// MODE 1: logits = vtot . u_hat, softmax over n within block, u from LDS stash.
template <int MODE>
__global__ __launch_bounds__(1024)
__attribute__((amdgpu_waves_per_eu(4, 4)))
void caps_pass(
    const float* __restrict__ W,     // [N][I][D][E]
    const float* __restrict__ x,     // [B][I][E]
    const float* __restrict__ vtot,  // [B][N][D]
    float* __restrict__ out,         // partials base or s (atomic)
    int use_part)
{
  const int t = threadIdx.x;
  const int w = t >> 6;      // wave 0..15 -> n = 4w+nn
  const int l = t & 63;
  const int q = l & 3;       // e-quarter
  const int dd = l >> 2;     // d (0..15); also owns d+16

  __shared__ float x_lds[B_ * E_];   // 1 KB: x[:, i, :]
  __shared__ float u_st[16 * 2048];  // 128 KB: [(nn*4+k)][t*2 + {0,1}]
  __shared__ float l2[N_ * 65];      // logit row-partials [n][b*4+row], pad
  __shared__ float c_lds[N_ * 17];   // c [n][b], pad

  float acc0[4][4], acc1[4][4];      // [nn][k], b=4k+q, d=dd / dd+16
#pragma unroll
  for (int nn = 0; nn < 4; ++nn)
#pragma unroll
    for (int k = 0; k < 4; ++k) { acc0[nn][k] = 0.f; acc1[nn][k] = 0.f; }

  const int i0 = blockIdx.x * IPER_;
  for (int ii = 0; ii < IPER_; ++ii) {
    const int i = i0 + ii;

    __syncthreads();  // prior i fully done (x_lds / u_st / l2 reuse)
    if (t < B_ * E_)
      x_lds[t] = x[((size_t)(t >> 4) * I_ + i) * E_ + (t & 15)];
    __syncthreads();

    const float4* Wbase = (const float4*)W + (((size_t)(4 * w) * I_ + i) << 7);

    // ---- phase A: compute u_hat; MODE0 accumulate, MODE1 stash + logits ----
    {
      float4 wa0 = Wbase[l], wa1 = Wbase[64 + l];
#pragma unroll
      for (int nn = 0; nn < 4; ++nn) {
        float4 wb0, wb1;
        if (nn < 3) {
          const float4* Wn = Wbase + (size_t)(nn + 1) * WN4_;
          wb0 = Wn[l]; wb1 = Wn[64 + l];
        }
        const int n = 4 * w + nn;
#pragma unroll
        for (int k = 0; k < 4; ++k) {
          float u0, u1;
          chunk_u(wa0, wa1, x_lds, k, q, u0, u1);
          if (MODE == 0) {
            acc0[nn][k] += u0;
            acc1[nn][k] += u1;
          } else {
            *(float2*)&u_st[(nn * 4 + k) * 2048 + 2 * t] = make_float2(u0, u1);
            const int b = 4 * k + q;
            const size_t va = (size_t)b * SROW_ + (size_t)n * D_ + dd;
            float lp = vtot[va] * u0 + vtot[va + 16] * u1;
            lp += dppf<0x124>(lp);   // + ror4
            lp += dppf<0x128>(lp);   // + ror8 -> sum over row's 4 dd
            if ((l & 12) == 0)       // one writer per (row, q)
              l2[n * 65 + b * 4 + (l >> 4)] = lp;
          }
        }
        if (nn < 3) { wa0 = wb0; wa1 = wb1; }
      }
    }

    if (MODE == 1) {
      __syncthreads();
      {
        // wave bw handles b=bw, lane j = n
        const int bw = t >> 6, j = t & 63;
        const int base = j * 65 + bw * 4;
        const float raw = l2[base] + l2[base + 1] + l2[base + 2] + l2[base + 3];
        float m = raw;
#pragma unroll
        for (int off = 32; off; off >>= 1) m = fmaxf(m, __shfl_xor(m, off));
        const float e = __expf(raw - m);
        float den = e;
#pragma unroll
        for (int off = 32; off; off >>= 1) den += __shfl_xor(den, off);
        c_lds[j * 17 + bw] = e / den;
      }
      __syncthreads();

      // ---- phase B: LDS-only — read stash, apply c, accumulate ----
#pragma unroll
      for (int nn = 0; nn < 4; ++nn) {
#pragma unroll
        for (int k = 0; k < 4; ++k) {
          const float2 u = *(const float2*)&u_st[(nn * 4 + k) * 2048 + 2 * t];
          const float cc = c_lds[(4 * w + nn) * 17 + 4 * k + q];
          acc0[nn][k] += cc * u.x;
          acc1[nn][k] += cc * u.y;
        }
      }
    }
  }

  // store: partial slice (non-atomic) or atomic accumulate
  const float sc = (MODE == 0) ? (1.f / 64.f) : 1.f;
  float* base = out + (use_part ? (size_t)blockIdx.x * PSTRIDE_ : 0);
#pragma unroll
  for (int nn = 0; nn < 4; ++nn) {
#pragma unroll
    for (int k = 0; k < 4; ++k) {
      const int b = 4 * k + q, n = 4 * w + nn;
      const size_t a = (size_t)b * SROW_ + (size_t)n * D_ + dd;
      if (use_part) {
        base[a] = acc0[nn][k] * sc;
        base[a + 16] = acc1[nn][k] * sc;
      } else {
        atomicAdd(&base[a], acc0[nn][k] * sc);
        atomicAdd(&base[a + 16], acc1[nn][k] * sc);
      }
    }
  }
}

__global__ void reduce_partials(const float* __restrict__ part,
                                float* __restrict__ s)
{
  const int t = blockIdx.x * blockDim.x + threadIdx.x;  // 32768 threads
  float sum = 0.f;
#pragma unroll 4
  for (int b = 0; b < GRID_; ++b) sum += part[(size_t)b * PSTRIDE_ + t];
  s[t] = sum;
}

// vtot[row] += squash(s[row]); rows are (b*64+n), 32 floats each
__global__ void caps_squash_acc(const float* __restrict__ s_in,
                                float* __restrict__ vtot)
{
  const int t = blockIdx.x * blockDim.x + threadIdx.x;
  if (t >= B_ * N_) return;
  float v[D_];
  float s2 = 0.f;
#pragma unroll
  for (int d = 0; d < D_; ++d) {
    v[d] = s_in[(size_t)t * D_ + d];
    s2 += v[d] * v[d];
  }
  const float f = s2 / ((1.f + s2) * sqrtf(s2 + EPS_));
#pragma unroll
  for (int d = 0; d < D_; ++d) vtot[(size_t)t * D_ + d] += v[d] * f;
}

__global__ void caps_squash_final(float* __restrict__ s_io)
{
  const int t = blockIdx.x * blockDim.x + threadIdx.x;
  if (t >= B_ * N_) return;
  float v[D_];
  float s2 = 0.f;
#pragma unroll
  for (int d = 0; d < D_; ++d) {
    v[d] = s_io[(size_t)t * D_ + d];
    s2 += v[d] * v[d];
  }
  const float f = s2 / ((1.f + s2) * sqrtf(s2 + EPS_));
#pragma unroll
  for (int d = 0; d < D_; ++d) s_io[(size_t)t * D_ + d] = v[d] * f;
}

extern "C" void kernel_launch(void* const* d_in, const int* in_sizes, int n_in,
                              void* d_out, int out_size, void* d_ws, size_t ws_size,
                              hipStream_t stream)
{
  const float* x = (const float*)d_in[0];  // [16][2048][16]
  const float* W = (const float*)d_in[1];  // [64][2048][32][16]
  float* s = (float*)d_out;                // [b][n][d] accumulator / output
  float* vtot = (float*)d_ws;              // 32768 floats
  float* part = vtot + NOUT_;              // 256 * 32768 floats if available

  const size_t need = ((size_t)NOUT_ + (size_t)GRID_ * PSTRIDE_) * sizeof(float);
  const int use_part = (ws_size >= need) ? 1 : 0;
  float* pass_out = use_part ? part : s;

  const size_t sbytes = (size_t)NOUT_ * sizeof(float);
  hipMemsetAsync(vtot, 0, sbytes, stream);

  // Round 1: c = 1/64
  if (!use_part) hipMemsetAsync(s, 0, sbytes, stream);
  caps_pass<0><<<GRID_, 1024, 0, stream>>>(W, x, vtot, pass_out, use_part);
  if (use_part) reduce_partials<<<128, 256, 0, stream>>>(part, s);
  caps_squash_acc<<<4, 256, 0, stream>>>(s, vtot);          // vtot = v0

  // Round 2: logits = v0 . u_hat
  if (!use_part) hipMemsetAsync(s, 0, sbytes, stream);
  caps_pass<1><<<GRID_, 1024, 0, stream>>>(W, x, vtot, pass_out, use_part);
  if (use_part) reduce_partials<<<128, 256, 0, stream>>>(part, s);
  caps_squash_acc<<<4, 256, 0, stream>>>(s, vtot);          // vtot = v0+v1

  // Round 3: logits = (v0+v1) . u_hat -> final squash in place
  if (!use_part) hipMemsetAsync(s, 0, sbytes, stream);
  caps_pass<1><<<GRID_, 1024, 0, stream>>>(W, x, vtot, pass_out, use_part);
  if (use_part) reduce_partials<<<128, 256, 0, stream>>>(part, s);
  caps_squash_final<<<4, 256, 0, stream>>>(s);
}